// Round 12
// baseline (89.711 us; speedup 1.0000x reference)
//
#include <hip/hip_runtime.h>
#include <hip/hip_bf16.h>
#include <stdint.h>
#include <math.h>

// Problem constants
#define VOCAB 1000000
#define D 128
#define NROWS 16384
#define NSAMP 8192
#define SSPLIT 16                      // flash: S split across 16 block groups
#define K1F 28.853900817779268f        // (1/TEMP)*log2(e) = 20*log2(e)
#define LOG2EF 1.4426950408889634f

// ws layout (bytes) — i8 fragment-major buffers
#define XF_OFF 0u                      // N*D i8 = 2 MB, frag-major, per-row qscale
#define EF_OFF 2097152u                // S*D i8 = 1 MB, frag-major, scale 127
#define PL_OFF 3145728u                // pos_logit fp32 [N] = 64 KB
#define SCX_OFF 3211264u               // per-row exp-arg scale fp32 [N] = 64 KB
#define PS_OFF 3276800u                // psum fp32 [SSPLIT][N] = 1 MB
#define FP_OFF 4325376u                // fin partials [64][2] = 512 B
#define CNT_OFF 4326400u               // counter (zeroed by prep each launch)

typedef __attribute__((ext_vector_type(4))) int i32x4;
typedef __attribute__((ext_vector_type(16))) int i32x16;

#if __has_builtin(__builtin_amdgcn_exp2f)
#define EXP2(x) __builtin_amdgcn_exp2f(x)
#else
#define EXP2(x) exp2f(x)
#endif

__device__ __forceinline__ void gl_lds16(const void* g, void* l) {
  __builtin_amdgcn_global_load_lds(
      (const __attribute__((address_space(1))) unsigned int*)g,
      (__attribute__((address_space(3))) unsigned int*)l, 16, 0, 0);
}

__device__ __forceinline__ float wave_sum(float v) {
#pragma unroll
  for (int o = 1; o < 64; o <<= 1) v += __shfl_xor(v, o);
  return v;
}

// Store one row's 2 consecutive dims (d = lane*2) as i8 into frag-major:
// element (row, d): kk = d>>5 (K-step of 32), sub = (d&31)>>4, j = d&15,
// byte = ((tile*4 + kk)*64 + ((sub<<5)|(row&31)))*16 + j.
__device__ __forceinline__ void store_frag_i8(char* __restrict__ base, int row,
                                              int lane, int bx, int by) {
  const int d = lane * 2;
  const int kk = d >> 5, sub = (d & 31) >> 4, j = d & 15;
  const int tile = row >> 5, lt = (sub << 5) | (row & 31);
  char* dst = base + (((size_t)(tile * 4 + kk) * 64 + lt) * 16 + j);
  dst[0] = (char)bx;
  dst[1] = (char)by;
}

// Prep: X rows -> i8 frag-major (per-row qscale=127/rawmax), scx[n] exp-arg
// scale, exact fp32 pos logit; E rows -> i8 frag-major (normalized, scale 127).
// 4 rows/wave with gathers issued up front (latency ILP). Block 0 zeroes cnt.
__global__ __launch_bounds__(256) void prep_kernel(
    const float* __restrict__ x, const int* __restrict__ tgt,
    const int* __restrict__ nid, const float* __restrict__ proj,
    char* __restrict__ xf, char* __restrict__ ef,
    float* __restrict__ pl, float* __restrict__ scx,
    unsigned int* __restrict__ cnt) {
  if (blockIdx.x == 0 && threadIdx.x == 0) *cnt = 0u;
  const int wave = threadIdx.x >> 6, lane = threadIdx.x & 63;
  if (blockIdx.x < 1024) {
    const int n0 = blockIdx.x * 16 + wave * 4;
    int tg[4];
    float2 xr[4], pr[4];
#pragma unroll
    for (int i = 0; i < 4; ++i) {
      const int t = tgt[n0 + i];
      tg[i] = t < 0 ? 0 : (t > VOCAB - 1 ? VOCAB - 1 : t);
      xr[i] = *reinterpret_cast<const float2*>(x + (size_t)(n0 + i) * D + lane * 2);
    }
#pragma unroll
    for (int i = 0; i < 4; ++i)
      pr[i] = *reinterpret_cast<const float2*>(proj + (size_t)tg[i] * D + lane * 2);
#pragma unroll
    for (int i = 0; i < 4; ++i) {
      float sx = xr[i].x * xr[i].x + xr[i].y * xr[i].y;
      float sp = pr[i].x * pr[i].x + pr[i].y * pr[i].y;
      float dt = xr[i].x * pr[i].x + xr[i].y * pr[i].y;
      float mx = fmaxf(fabsf(xr[i].x), fabsf(xr[i].y));
#pragma unroll
      for (int o = 1; o < 64; o <<= 1) {
        sx += __shfl_xor(sx, o);
        sp += __shfl_xor(sp, o);
        dt += __shfl_xor(dt, o);
        mx = fmaxf(mx, __shfl_xor(mx, o));
      }
      const float norm = sqrtf(sx) + 1e-12f;
      if (lane == 0) {
        pl[n0 + i] = dt / (norm * (sqrtf(sp) + 1e-12f)) * 20.0f;  // /TEMP
        scx[n0 + i] = K1F * (mx + 1e-20f) / (16129.0f * norm);    // 127^2
      }
      const float qs = 127.0f / (mx + 1e-20f);  // raw-domain quant scale
      store_frag_i8(xf, n0 + i, lane, (int)rintf(xr[i].x * qs),
                    (int)rintf(xr[i].y * qs));
    }
  } else {
    const int s0 = (blockIdx.x - 1024) * 16 + wave * 4;
    float2 er[4];
#pragma unroll
    for (int i = 0; i < 4; ++i) {
      const int id = nid[s0 + i];
      er[i] = *reinterpret_cast<const float2*>(proj + (size_t)id * D + lane * 2);
    }
#pragma unroll
    for (int i = 0; i < 4; ++i) {
      const float qs =
          127.0f / (sqrtf(wave_sum(er[i].x * er[i].x + er[i].y * er[i].y)) + 1e-12f);
      store_frag_i8(ef, s0 + i, lane, (int)rintf(er[i].x * qs),
                    (int)rintf(er[i].y * qs));
    }
  }
}

// Flash kernel, i8 F=2, SSPLIT=16 (identical to R10). PROBE: launched 3x this
// round to measure its duration via dur-delta (idempotent psum overwrite).
__global__ __launch_bounds__(256, 4) void flash_kernel(
    const char* __restrict__ xf, const char* __restrict__ ef,
    const float* __restrict__ scx, float* __restrict__ psum) {
  __shared__ __align__(16) char lds[2][8192];
  const int tid = threadIdx.x, wave = tid >> 6, lane = tid & 63;
  const int nb = blockIdx.x & 63, ss = blockIdx.x >> 6;
  const int nbase = nb * 256 + wave * 64;

  // B fragments (X): 2 n-frags (64 rows) x 4 k-steps, from frag-major xf.
  i32x4 bq[2][4];
#pragma unroll
  for (int nf = 0; nf < 2; ++nf) {
    const char* p = xf + ((size_t)(nb * 8 + wave * 2 + nf) * 4096) + lane * 16;
#pragma unroll
    for (int kk = 0; kk < 4; ++kk)
      bq[nf][kk] = *reinterpret_cast<const i32x4*>(p + kk * 1024);
  }
  const float scx0 = scx[nbase + (lane & 31)];
  const float scx1 = scx[nbase + 32 + (lane & 31)];

  const char* esrc = ef + (size_t)ss * 65536;  // 512-s slice, 128 B/row
  float acc0 = 0.f, acc1 = 0.f;

  {  // stage supertile 0 (8 KB: 256 threads x 2 x 16 B)
    const char* g = esrc + tid * 16;
    char* l = &lds[0][0] + tid * 16;
    gl_lds16(g, l);
    gl_lds16(g + 4096, l + 4096);
  }
  __syncthreads();

  for (int st = 0; st < 8; ++st) {
    if (st < 7) {  // prefetch next supertile into the other buffer
      const char* g = esrc + (size_t)(st + 1) * 8192 + tid * 16;
      char* l = &lds[(st + 1) & 1][0] + tid * 16;
      gl_lds16(g, l);
      gl_lds16(g + 4096, l + 4096);
    }
    const char* cb = &lds[st & 1][0];
#pragma unroll
    for (int tt = 0; tt < 2; ++tt) {
      i32x16 c0, c1;
#pragma unroll
      for (int r = 0; r < 16; ++r) { c0[r] = 0; c1[r] = 0; }
      const char* ab = cb + tt * 4096 + lane * 16;
#pragma unroll
      for (int kk = 0; kk < 4; ++kk) {
        i32x4 a = *reinterpret_cast<const i32x4*>(ab + kk * 1024);
        c0 = __builtin_amdgcn_mfma_i32_32x32x32_i8(a, bq[0][kk], c0, 0, 0, 0);
        c1 = __builtin_amdgcn_mfma_i32_32x32x32_i8(a, bq[1][kk], c1, 0, 0, 0);
      }
      float e0[16], e1[16];
#pragma unroll
      for (int r = 0; r < 16; ++r) {
        e0[r] = EXP2((float)c0[r] * scx0);
        e1[r] = EXP2((float)c1[r] * scx1);
      }
#pragma unroll
      for (int s2 = 8; s2; s2 >>= 1)
#pragma unroll
        for (int r = 0; r < s2; ++r) { e0[r] += e0[r + s2]; e1[r] += e1[r + s2]; }
      acc0 += e0[0];
      acc1 += e1[0];
    }
    __syncthreads();
  }

  // lanes l and l+32 hold different s-rows of the same column n: combine.
  acc0 += __shfl_xor(acc0, 32);
  acc1 += __shfl_xor(acc1, 32);
  if (lane < 32) {
    psum[(size_t)ss * NROWS + nbase + lane] = acc0;
    psum[(size_t)ss * NROWS + nbase + 32 + lane] = acc1;
  }
}

// Finish (with fused final): 64 blocks x 256 rows. Per-row CE + weighted
// partials; last-arriving block (64 ACQ_REL bumps total) reduces to out[0].
__global__ __launch_bounds__(256) void finish_kernel(
    const float* __restrict__ psum, const float* __restrict__ pl,
    const int* __restrict__ tgt, const float* __restrict__ wts,
    float* __restrict__ fin, unsigned int* __restrict__ cnt,
    float* __restrict__ out) {
  const int n = blockIdx.x * 256 + threadIdx.x;
  float tot = 0.f;
#pragma unroll
  for (int s = 0; s < SSPLIT; ++s) tot += psum[(size_t)s * NROWS + n];
  const float p = pl[n];
  tot += EXP2(p * LOG2EF);             // + exp(pos_logit), unshifted
  const float ce = logf(tot) - p;      // logZ - pos_logit
  const float w = wts[n] * (tgt[n] != -100 ? 1.f : 0.f);
  float a = wave_sum(ce * w);
  float b = wave_sum(w);
  __shared__ float sa[4], sb[4];
  __shared__ int last;
  const int wave = threadIdx.x >> 6, lane = threadIdx.x & 63;
  if (lane == 0) { sa[wave] = a; sb[wave] = b; }
  __syncthreads();
  if (threadIdx.x == 0) {
    __hip_atomic_store(&fin[blockIdx.x * 2], sa[0] + sa[1] + sa[2] + sa[3],
                       __ATOMIC_RELAXED, __HIP_MEMORY_SCOPE_AGENT);
    __hip_atomic_store(&fin[blockIdx.x * 2 + 1], sb[0] + sb[1] + sb[2] + sb[3],
                       __ATOMIC_RELAXED, __HIP_MEMORY_SCOPE_AGENT);
    const unsigned int old = __hip_atomic_fetch_add(cnt, 1u, __ATOMIC_ACQ_REL,
                                                    __HIP_MEMORY_SCOPE_AGENT);
    last = (old == 63u);
  }
  __syncthreads();
  if (last && threadIdx.x < 64) {  // wave 0 of last block reduces 64 pairs
    const float A = wave_sum(__hip_atomic_load(&fin[threadIdx.x * 2],
                                               __ATOMIC_RELAXED,
                                               __HIP_MEMORY_SCOPE_AGENT));
    const float B = wave_sum(__hip_atomic_load(&fin[threadIdx.x * 2 + 1],
                                               __ATOMIC_RELAXED,
                                               __HIP_MEMORY_SCOPE_AGENT));
    if (threadIdx.x == 0) out[0] = A / fmaxf(B, 1e-12f);
  }
}

extern "C" void kernel_launch(void* const* d_in, const int* in_sizes, int n_in,
                              void* d_out, int out_size, void* d_ws, size_t ws_size,
                              hipStream_t stream) {
  const float* x    = (const float*)d_in[0];
  const int*   tgt  = (const int*)d_in[1];
  const int*   nid  = (const int*)d_in[2];
  const float* wts  = (const float*)d_in[3];
  const float* proj = (const float*)d_in[4];
  float* out = (float*)d_out;
  char* ws = (char*)d_ws;
  char* xf = ws + XF_OFF;
  char* ef = ws + EF_OFF;
  float* pl   = (float*)(ws + PL_OFF);
  float* scx  = (float*)(ws + SCX_OFF);
  float* psum = (float*)(ws + PS_OFF);
  float* fin  = (float*)(ws + FP_OFF);
  unsigned int* cnt = (unsigned int*)(ws + CNT_OFF);

  hipLaunchKernelGGL(prep_kernel, dim3(1024 + 512), dim3(256), 0, stream,
                     x, tgt, nid, proj, xf, ef, pl, scx, cnt);
  // PROBE: flash launched 3x (idempotent). dur_delta vs R10 = 2 * flash_time.
  hipLaunchKernelGGL(flash_kernel, dim3(64 * SSPLIT), dim3(256), 0, stream,
                     xf, ef, scx, psum);
  hipLaunchKernelGGL(flash_kernel, dim3(64 * SSPLIT), dim3(256), 0, stream,
                     xf, ef, scx, psum);
  hipLaunchKernelGGL(flash_kernel, dim3(64 * SSPLIT), dim3(256), 0, stream,
                     xf, ef, scx, psum);
  hipLaunchKernelGGL(finish_kernel, dim3(NROWS / 256), dim3(256), 0, stream,
                     psum, pl, tgt, wts, fin, cnt, out);
}

// Round 13
// 43.968 us; speedup vs baseline: 2.0404x; 2.0404x over previous
//
#include <hip/hip_runtime.h>
#include <hip/hip_bf16.h>
#include <stdint.h>
#include <math.h>

// Problem constants
#define VOCAB 1000000
#define D 128
#define NROWS 16384
#define NSAMP 8192
#define SSPLIT 16                      // flash: S split across 16 block groups
#define K1F 28.853900817779268f        // (1/TEMP)*log2(e) = 20*log2(e)
#define LOG2EF 1.4426950408889634f

// ws layout (bytes) — i8 fragment-major buffers
#define XF_OFF 0u                      // N*D i8 = 2 MB, frag-major, per-row qscale
#define EF_OFF 2097152u                // S*D i8 = 1 MB, frag-major, scale 127
#define PL_OFF 3145728u                // pos_logit fp32 [N] = 64 KB
#define SCX_OFF 3211264u               // per-row exp-arg scale fp32 [N] = 64 KB
#define PS_OFF 3276800u                // psum fp32 [SSPLIT][N] = 1 MB
#define FP_OFF 4325376u                // fin partials [64][2] = 512 B
#define CNT_OFF 4326400u               // counter (zeroed by prep each launch)

typedef __attribute__((ext_vector_type(4))) int i32x4;
typedef __attribute__((ext_vector_type(16))) int i32x16;

#if __has_builtin(__builtin_amdgcn_exp2f)
#define EXP2(x) __builtin_amdgcn_exp2f(x)
#else
#define EXP2(x) exp2f(x)
#endif

__device__ __forceinline__ float wave_sum(float v) {
#pragma unroll
  for (int o = 1; o < 64; o <<= 1) v += __shfl_xor(v, o);
  return v;
}

// Store one row's 2 consecutive dims (d = lane*2) as i8 into frag-major:
// element (row, d): kk = d>>5 (K-step of 32), sub = (d&31)>>4, j = d&15,
// byte = ((tile*4 + kk)*64 + ((sub<<5)|(row&31)))*16 + j.
__device__ __forceinline__ void store_frag_i8(char* __restrict__ base, int row,
                                              int lane, int bx, int by) {
  const int d = lane * 2;
  const int kk = d >> 5, sub = (d & 31) >> 4, j = d & 15;
  const int tile = row >> 5, lt = (sub << 5) | (row & 31);
  char* dst = base + (((size_t)(tile * 4 + kk) * 64 + lt) * 16 + j);
  dst[0] = (char)bx;
  dst[1] = (char)by;
}

// Prep: X rows -> i8 frag-major (per-row qscale=127/rawmax), scx[n] exp-arg
// scale, exact fp32 pos logit; E rows -> i8 frag-major (normalized, scale 127).
// 4 rows/wave with gathers issued up front (latency ILP). Block 0 zeroes cnt.
__global__ __launch_bounds__(256) void prep_kernel(
    const float* __restrict__ x, const int* __restrict__ tgt,
    const int* __restrict__ nid, const float* __restrict__ proj,
    char* __restrict__ xf, char* __restrict__ ef,
    float* __restrict__ pl, float* __restrict__ scx,
    unsigned int* __restrict__ cnt) {
  if (blockIdx.x == 0 && threadIdx.x == 0) *cnt = 0u;
  const int wave = threadIdx.x >> 6, lane = threadIdx.x & 63;
  if (blockIdx.x < 1024) {
    const int n0 = blockIdx.x * 16 + wave * 4;
    int tg[4];
    float2 xr[4], pr[4];
#pragma unroll
    for (int i = 0; i < 4; ++i) {
      const int t = tgt[n0 + i];
      tg[i] = t < 0 ? 0 : (t > VOCAB - 1 ? VOCAB - 1 : t);
      xr[i] = *reinterpret_cast<const float2*>(x + (size_t)(n0 + i) * D + lane * 2);
    }
#pragma unroll
    for (int i = 0; i < 4; ++i)
      pr[i] = *reinterpret_cast<const float2*>(proj + (size_t)tg[i] * D + lane * 2);
#pragma unroll
    for (int i = 0; i < 4; ++i) {
      float sx = xr[i].x * xr[i].x + xr[i].y * xr[i].y;
      float sp = pr[i].x * pr[i].x + pr[i].y * pr[i].y;
      float dt = xr[i].x * pr[i].x + xr[i].y * pr[i].y;
      float mx = fmaxf(fabsf(xr[i].x), fabsf(xr[i].y));
#pragma unroll
      for (int o = 1; o < 64; o <<= 1) {
        sx += __shfl_xor(sx, o);
        sp += __shfl_xor(sp, o);
        dt += __shfl_xor(dt, o);
        mx = fmaxf(mx, __shfl_xor(mx, o));
      }
      const float norm = sqrtf(sx) + 1e-12f;
      if (lane == 0) {
        pl[n0 + i] = dt / (norm * (sqrtf(sp) + 1e-12f)) * 20.0f;  // /TEMP
        scx[n0 + i] = K1F * (mx + 1e-20f) / (16129.0f * norm);    // 127^2
      }
      const float qs = 127.0f / (mx + 1e-20f);  // raw-domain quant scale
      store_frag_i8(xf, n0 + i, lane, (int)rintf(xr[i].x * qs),
                    (int)rintf(xr[i].y * qs));
    }
  } else {
    const int s0 = (blockIdx.x - 1024) * 16 + wave * 4;
    float2 er[4];
#pragma unroll
    for (int i = 0; i < 4; ++i) {
      const int id = nid[s0 + i];
      er[i] = *reinterpret_cast<const float2*>(proj + (size_t)id * D + lane * 2);
    }
#pragma unroll
    for (int i = 0; i < 4; ++i) {
      const float qs =
          127.0f / (sqrtf(wave_sum(er[i].x * er[i].x + er[i].y * er[i].y)) + 1e-12f);
      store_frag_i8(ef, s0 + i, lane, (int)rintf(er[i].x * qs),
                    (int)rintf(er[i].y * qs));
    }
  }
}

// Flash kernel, NO-LDS variant: ef (1 MB) is L2-resident, so A-fragments are
// read directly from global (L1 filters 4x intra-block reuse). No barriers,
// no staging -> waves free-run and destagger; VALU (exp2 path, the floor)
// stays fed. Per 32-row s-tile: 4 b128 loads + 8 MFMAs + 32 exp2/adds.
__global__ __launch_bounds__(256, 4) void flash_kernel(
    const char* __restrict__ xf, const char* __restrict__ ef,
    const float* __restrict__ scx, float* __restrict__ psum) {
  const int tid = threadIdx.x, wave = tid >> 6, lane = tid & 63;
  const int nb = blockIdx.x & 63, ss = blockIdx.x >> 6;
  const int nbase = nb * 256 + wave * 64;

  // B fragments (X): 2 n-frags (64 rows) x 4 k-steps, from frag-major xf.
  i32x4 bq[2][4];
#pragma unroll
  for (int nf = 0; nf < 2; ++nf) {
    const char* p = xf + ((size_t)(nb * 8 + wave * 2 + nf) * 4096) + lane * 16;
#pragma unroll
    for (int kk = 0; kk < 4; ++kk)
      bq[nf][kk] = *reinterpret_cast<const i32x4*>(p + kk * 1024);
  }
  const float scx0 = scx[nbase + (lane & 31)];
  const float scx1 = scx[nbase + 32 + (lane & 31)];

  // per-lane base into this block's 512-s slice (16 s-tiles of 4 KB each)
  const char* esrc = ef + (size_t)ss * 65536 + lane * 16;
  float acc0 = 0.f, acc1 = 0.f;

  for (int t = 0; t < 16; ++t) {
    const char* ab = esrc + (size_t)t * 4096;
    const i32x4 a0 = *reinterpret_cast<const i32x4*>(ab);
    const i32x4 a1 = *reinterpret_cast<const i32x4*>(ab + 1024);
    const i32x4 a2 = *reinterpret_cast<const i32x4*>(ab + 2048);
    const i32x4 a3 = *reinterpret_cast<const i32x4*>(ab + 3072);
    i32x16 c0, c1;
#pragma unroll
    for (int r = 0; r < 16; ++r) { c0[r] = 0; c1[r] = 0; }
    c0 = __builtin_amdgcn_mfma_i32_32x32x32_i8(a0, bq[0][0], c0, 0, 0, 0);
    c1 = __builtin_amdgcn_mfma_i32_32x32x32_i8(a0, bq[1][0], c1, 0, 0, 0);
    c0 = __builtin_amdgcn_mfma_i32_32x32x32_i8(a1, bq[0][1], c0, 0, 0, 0);
    c1 = __builtin_amdgcn_mfma_i32_32x32x32_i8(a1, bq[1][1], c1, 0, 0, 0);
    c0 = __builtin_amdgcn_mfma_i32_32x32x32_i8(a2, bq[0][2], c0, 0, 0, 0);
    c1 = __builtin_amdgcn_mfma_i32_32x32x32_i8(a2, bq[1][2], c1, 0, 0, 0);
    c0 = __builtin_amdgcn_mfma_i32_32x32x32_i8(a3, bq[0][3], c0, 0, 0, 0);
    c1 = __builtin_amdgcn_mfma_i32_32x32x32_i8(a3, bq[1][3], c1, 0, 0, 0);
    float e0[16], e1[16];
#pragma unroll
    for (int r = 0; r < 16; ++r) {
      e0[r] = EXP2((float)c0[r] * scx0);
      e1[r] = EXP2((float)c1[r] * scx1);
    }
#pragma unroll
    for (int s2 = 8; s2; s2 >>= 1)
#pragma unroll
      for (int r = 0; r < s2; ++r) { e0[r] += e0[r + s2]; e1[r] += e1[r + s2]; }
    acc0 += e0[0];
    acc1 += e1[0];
  }

  // lanes l and l+32 hold different s-rows of the same column n: combine.
  acc0 += __shfl_xor(acc0, 32);
  acc1 += __shfl_xor(acc1, 32);
  if (lane < 32) {
    psum[(size_t)ss * NROWS + nbase + lane] = acc0;
    psum[(size_t)ss * NROWS + nbase + 32 + lane] = acc1;
  }
}

// Finish (with fused final): 64 blocks x 256 rows. Per-row CE + weighted
// partials; last-arriving block (64 ACQ_REL bumps total) reduces to out[0].
__global__ __launch_bounds__(256) void finish_kernel(
    const float* __restrict__ psum, const float* __restrict__ pl,
    const int* __restrict__ tgt, const float* __restrict__ wts,
    float* __restrict__ fin, unsigned int* __restrict__ cnt,
    float* __restrict__ out) {
  const int n = blockIdx.x * 256 + threadIdx.x;
  float tot = 0.f;
#pragma unroll
  for (int s = 0; s < SSPLIT; ++s) tot += psum[(size_t)s * NROWS + n];
  const float p = pl[n];
  tot += EXP2(p * LOG2EF);             // + exp(pos_logit), unshifted
  const float ce = logf(tot) - p;      // logZ - pos_logit
  const float w = wts[n] * (tgt[n] != -100 ? 1.f : 0.f);
  float a = wave_sum(ce * w);
  float b = wave_sum(w);
  __shared__ float sa[4], sb[4];
  __shared__ int last;
  const int wave = threadIdx.x >> 6, lane = threadIdx.x & 63;
  if (lane == 0) { sa[wave] = a; sb[wave] = b; }
  __syncthreads();
  if (threadIdx.x == 0) {
    __hip_atomic_store(&fin[blockIdx.x * 2], sa[0] + sa[1] + sa[2] + sa[3],
                       __ATOMIC_RELAXED, __HIP_MEMORY_SCOPE_AGENT);
    __hip_atomic_store(&fin[blockIdx.x * 2 + 1], sb[0] + sb[1] + sb[2] + sb[3],
                       __ATOMIC_RELAXED, __HIP_MEMORY_SCOPE_AGENT);
    const unsigned int old = __hip_atomic_fetch_add(cnt, 1u, __ATOMIC_ACQ_REL,
                                                    __HIP_MEMORY_SCOPE_AGENT);
    last = (old == 63u);
  }
  __syncthreads();
  if (last && threadIdx.x < 64) {  // wave 0 of last block reduces 64 pairs
    const float A = wave_sum(__hip_atomic_load(&fin[threadIdx.x * 2],
                                               __ATOMIC_RELAXED,
                                               __HIP_MEMORY_SCOPE_AGENT));
    const float B = wave_sum(__hip_atomic_load(&fin[threadIdx.x * 2 + 1],
                                               __ATOMIC_RELAXED,
                                               __HIP_MEMORY_SCOPE_AGENT));
    if (threadIdx.x == 0) out[0] = A / fmaxf(B, 1e-12f);
  }
}

extern "C" void kernel_launch(void* const* d_in, const int* in_sizes, int n_in,
                              void* d_out, int out_size, void* d_ws, size_t ws_size,
                              hipStream_t stream) {
  const float* x    = (const float*)d_in[0];
  const int*   tgt  = (const int*)d_in[1];
  const int*   nid  = (const int*)d_in[2];
  const float* wts  = (const float*)d_in[3];
  const float* proj = (const float*)d_in[4];
  float* out = (float*)d_out;
  char* ws = (char*)d_ws;
  char* xf = ws + XF_OFF;
  char* ef = ws + EF_OFF;
  float* pl   = (float*)(ws + PL_OFF);
  float* scx  = (float*)(ws + SCX_OFF);
  float* psum = (float*)(ws + PS_OFF);
  float* fin  = (float*)(ws + FP_OFF);
  unsigned int* cnt = (unsigned int*)(ws + CNT_OFF);

  hipLaunchKernelGGL(prep_kernel, dim3(1024 + 512), dim3(256), 0, stream,
                     x, tgt, nid, proj, xf, ef, pl, scx, cnt);
  hipLaunchKernelGGL(flash_kernel, dim3(64 * SSPLIT), dim3(256), 0, stream,
                     xf, ef, scx, psum);
  hipLaunchKernelGGL(finish_kernel, dim3(NROWS / 256), dim3(256), 0, stream,
                     psum, pl, tgt, wts, fin, cnt, out);
}

// Round 14
// 41.587 us; speedup vs baseline: 2.1572x; 1.0572x over previous
//
#include <hip/hip_runtime.h>
#include <hip/hip_bf16.h>
#include <stdint.h>
#include <math.h>

// Problem constants
#define VOCAB 1000000
#define D 128
#define NROWS 16384
#define NSAMP 8192
#define SSPLIT 16                      // flash: S split across 16 block groups
#define K1F 28.853900817779268f        // (1/TEMP)*log2(e) = 20*log2(e)
#define LOG2EF 1.4426950408889634f

// ws layout (bytes) — i8 fragment-major buffers
#define XF_OFF 0u                      // N*D i8 = 2 MB, frag-major, per-row qscale
#define EF_OFF 2097152u                // S*D i8 = 1 MB, frag-major, scale 127
#define PL_OFF 3145728u                // pos_logit fp32 [N] = 64 KB
#define SCX_OFF 3211264u               // per-row exp-arg scale fp32 [N] = 64 KB
#define PS_OFF 3276800u                // psum fp32 [SSPLIT][N] = 1 MB
#define FP_OFF 4325376u                // fin partials [64][2] = 512 B
#define CNT_OFF 4326400u               // counter (zeroed by prep each launch)

typedef __attribute__((ext_vector_type(4))) int i32x4;
typedef __attribute__((ext_vector_type(16))) int i32x16;

#if __has_builtin(__builtin_amdgcn_exp2f)
#define EXP2(x) __builtin_amdgcn_exp2f(x)
#else
#define EXP2(x) exp2f(x)
#endif

__device__ __forceinline__ float wave_sum(float v) {
#pragma unroll
  for (int o = 1; o < 64; o <<= 1) v += __shfl_xor(v, o);
  return v;
}

// Store one row's 2 consecutive dims (d = lane*2) as i8 into frag-major:
// element (row, d): kk = d>>5 (K-step of 32), sub = (d&31)>>4, j = d&15,
// byte = ((tile*4 + kk)*64 + ((sub<<5)|(row&31)))*16 + j.
__device__ __forceinline__ void store_frag_i8(char* __restrict__ base, int row,
                                              int lane, int bx, int by) {
  const int d = lane * 2;
  const int kk = d >> 5, sub = (d & 31) >> 4, j = d & 15;
  const int tile = row >> 5, lt = (sub << 5) | (row & 31);
  char* dst = base + (((size_t)(tile * 4 + kk) * 64 + lt) * 16 + j);
  dst[0] = (char)bx;
  dst[1] = (char)by;
}

// Prep: X rows -> i8 frag-major (per-row qscale=127/rawmax), scx[n] exp-arg
// scale, exact fp32 pos logit; E rows -> i8 frag-major (normalized, scale 127).
// 4 rows/wave with gathers issued up front (latency ILP). Block 0 zeroes cnt.
__global__ __launch_bounds__(256) void prep_kernel(
    const float* __restrict__ x, const int* __restrict__ tgt,
    const int* __restrict__ nid, const float* __restrict__ proj,
    char* __restrict__ xf, char* __restrict__ ef,
    float* __restrict__ pl, float* __restrict__ scx,
    unsigned int* __restrict__ cnt) {
  if (blockIdx.x == 0 && threadIdx.x == 0) *cnt = 0u;
  const int wave = threadIdx.x >> 6, lane = threadIdx.x & 63;
  if (blockIdx.x < 1024) {
    const int n0 = blockIdx.x * 16 + wave * 4;
    int tg[4];
    float2 xr[4], pr[4];
#pragma unroll
    for (int i = 0; i < 4; ++i) {
      const int t = tgt[n0 + i];
      tg[i] = t < 0 ? 0 : (t > VOCAB - 1 ? VOCAB - 1 : t);
      xr[i] = *reinterpret_cast<const float2*>(x + (size_t)(n0 + i) * D + lane * 2);
    }
#pragma unroll
    for (int i = 0; i < 4; ++i)
      pr[i] = *reinterpret_cast<const float2*>(proj + (size_t)tg[i] * D + lane * 2);
#pragma unroll
    for (int i = 0; i < 4; ++i) {
      float sx = xr[i].x * xr[i].x + xr[i].y * xr[i].y;
      float sp = pr[i].x * pr[i].x + pr[i].y * pr[i].y;
      float dt = xr[i].x * pr[i].x + xr[i].y * pr[i].y;
      float mx = fmaxf(fabsf(xr[i].x), fabsf(xr[i].y));
#pragma unroll
      for (int o = 1; o < 64; o <<= 1) {
        sx += __shfl_xor(sx, o);
        sp += __shfl_xor(sp, o);
        dt += __shfl_xor(dt, o);
        mx = fmaxf(mx, __shfl_xor(mx, o));
      }
      const float norm = sqrtf(sx) + 1e-12f;
      if (lane == 0) {
        pl[n0 + i] = dt / (norm * (sqrtf(sp) + 1e-12f)) * 20.0f;  // /TEMP
        scx[n0 + i] = K1F * (mx + 1e-20f) / (16129.0f * norm);    // 127^2
      }
      const float qs = 127.0f / (mx + 1e-20f);  // raw-domain quant scale
      store_frag_i8(xf, n0 + i, lane, (int)rintf(xr[i].x * qs),
                    (int)rintf(xr[i].y * qs));
    }
  } else {
    const int s0 = (blockIdx.x - 1024) * 16 + wave * 4;
    float2 er[4];
#pragma unroll
    for (int i = 0; i < 4; ++i) {
      const int id = nid[s0 + i];
      er[i] = *reinterpret_cast<const float2*>(proj + (size_t)id * D + lane * 2);
    }
#pragma unroll
    for (int i = 0; i < 4; ++i) {
      const float qs =
          127.0f / (sqrtf(wave_sum(er[i].x * er[i].x + er[i].y * er[i].y)) + 1e-12f);
      store_frag_i8(ef, s0 + i, lane, (int)rintf(er[i].x * qs),
                    (int)rintf(er[i].y * qs));
    }
  }
}

#define LD16(p) (*reinterpret_cast<const i32x4*>(p))

// Process one 32-s tile held in registers A0..A3: 8 MFMAs + exp-accumulate.
#define PROC(A0_, A1_, A2_, A3_)                                             \
  do {                                                                       \
    i32x16 c0, c1;                                                           \
    _Pragma("unroll") for (int r = 0; r < 16; ++r) { c0[r] = 0; c1[r] = 0; } \
    c0 = __builtin_amdgcn_mfma_i32_32x32x32_i8(A0_, bq[0][0], c0, 0, 0, 0);  \
    c1 = __builtin_amdgcn_mfma_i32_32x32x32_i8(A0_, bq[1][0], c1, 0, 0, 0);  \
    c0 = __builtin_amdgcn_mfma_i32_32x32x32_i8(A1_, bq[0][1], c0, 0, 0, 0);  \
    c1 = __builtin_amdgcn_mfma_i32_32x32x32_i8(A1_, bq[1][1], c1, 0, 0, 0);  \
    c0 = __builtin_amdgcn_mfma_i32_32x32x32_i8(A2_, bq[0][2], c0, 0, 0, 0);  \
    c1 = __builtin_amdgcn_mfma_i32_32x32x32_i8(A2_, bq[1][2], c1, 0, 0, 0);  \
    c0 = __builtin_amdgcn_mfma_i32_32x32x32_i8(A3_, bq[0][3], c0, 0, 0, 0);  \
    c1 = __builtin_amdgcn_mfma_i32_32x32x32_i8(A3_, bq[1][3], c1, 0, 0, 0);  \
    _Pragma("unroll") for (int r = 0; r < 8; ++r) {                          \
      acc0a += EXP2((float)c0[2 * r] * scx0);                                \
      acc0b += EXP2((float)c0[2 * r + 1] * scx0);                            \
      acc1a += EXP2((float)c1[2 * r] * scx1);                                \
      acc1b += EXP2((float)c1[2 * r + 1] * scx1);                            \
    }                                                                        \
  } while (0)

// Flash kernel, no-LDS + explicit 1-deep register prefetch (unroll-2
// ping-pong, named regs). Loads for tile t+1 issue BEFORE tile t's MFMA+exp
// phase, so L2 latency hides under own-wave compute (counted-vmcnt pattern —
// compiler emits vmcnt(4) for the older quad while the newer 4 stay in
// flight). ~116 VGPR -> fits the (256,4)/128 cap, 4 waves/SIMD.
__global__ __launch_bounds__(256, 4) void flash_kernel(
    const char* __restrict__ xf, const char* __restrict__ ef,
    const float* __restrict__ scx, float* __restrict__ psum) {
  const int tid = threadIdx.x, wave = tid >> 6, lane = tid & 63;
  const int nb = blockIdx.x & 63, ss = blockIdx.x >> 6;
  const int nbase = nb * 256 + wave * 64;

  // B fragments (X): 2 n-frags (64 rows) x 4 k-steps, from frag-major xf.
  i32x4 bq[2][4];
#pragma unroll
  for (int nf = 0; nf < 2; ++nf) {
    const char* p = xf + ((size_t)(nb * 8 + wave * 2 + nf) * 4096) + lane * 16;
#pragma unroll
    for (int kk = 0; kk < 4; ++kk)
      bq[nf][kk] = *reinterpret_cast<const i32x4*>(p + kk * 1024);
  }
  const float scx0 = scx[nbase + (lane & 31)];
  const float scx1 = scx[nbase + 32 + (lane & 31)];

  // per-lane base into this block's 512-s slice (16 s-tiles of 4 KB each)
  const char* esrc = ef + (size_t)ss * 65536 + lane * 16;
  float acc0a = 0.f, acc0b = 0.f, acc1a = 0.f, acc1b = 0.f;

  i32x4 A0 = LD16(esrc), A1 = LD16(esrc + 1024),
        A2 = LD16(esrc + 2048), A3 = LD16(esrc + 3072);
  i32x4 B0, B1, B2, B3;

#pragma unroll
  for (int t = 0; t < 16; t += 2) {
    {  // prefetch tile t+1 (always valid: t+1 <= 15)
      const char* p = esrc + (size_t)(t + 1) * 4096;
      B0 = LD16(p); B1 = LD16(p + 1024); B2 = LD16(p + 2048); B3 = LD16(p + 3072);
    }
    PROC(A0, A1, A2, A3);
    if (t + 2 < 16) {  // prefetch tile t+2
      const char* p = esrc + (size_t)(t + 2) * 4096;
      A0 = LD16(p); A1 = LD16(p + 1024); A2 = LD16(p + 2048); A3 = LD16(p + 3072);
    }
    PROC(B0, B1, B2, B3);
  }

  float acc0 = acc0a + acc0b, acc1 = acc1a + acc1b;
  // lanes l and l+32 hold different s-rows of the same column n: combine.
  acc0 += __shfl_xor(acc0, 32);
  acc1 += __shfl_xor(acc1, 32);
  if (lane < 32) {
    psum[(size_t)ss * NROWS + nbase + lane] = acc0;
    psum[(size_t)ss * NROWS + nbase + 32 + lane] = acc1;
  }
}

// Finish (with fused final): 64 blocks x 256 rows. Per-row CE + weighted
// partials; last-arriving block (64 ACQ_REL bumps total) reduces to out[0].
__global__ __launch_bounds__(256) void finish_kernel(
    const float* __restrict__ psum, const float* __restrict__ pl,
    const int* __restrict__ tgt, const float* __restrict__ wts,
    float* __restrict__ fin, unsigned int* __restrict__ cnt,
    float* __restrict__ out) {
  const int n = blockIdx.x * 256 + threadIdx.x;
  float tot = 0.f;
#pragma unroll
  for (int s = 0; s < SSPLIT; ++s) tot += psum[(size_t)s * NROWS + n];
  const float p = pl[n];
  tot += EXP2(p * LOG2EF);             // + exp(pos_logit), unshifted
  const float ce = logf(tot) - p;      // logZ - pos_logit
  const float w = wts[n] * (tgt[n] != -100 ? 1.f : 0.f);
  float a = wave_sum(ce * w);
  float b = wave_sum(w);
  __shared__ float sa[4], sb[4];
  __shared__ int last;
  const int wave = threadIdx.x >> 6, lane = threadIdx.x & 63;
  if (lane == 0) { sa[wave] = a; sb[wave] = b; }
  __syncthreads();
  if (threadIdx.x == 0) {
    __hip_atomic_store(&fin[blockIdx.x * 2], sa[0] + sa[1] + sa[2] + sa[3],
                       __ATOMIC_RELAXED, __HIP_MEMORY_SCOPE_AGENT);
    __hip_atomic_store(&fin[blockIdx.x * 2 + 1], sb[0] + sb[1] + sb[2] + sb[3],
                       __ATOMIC_RELAXED, __HIP_MEMORY_SCOPE_AGENT);
    const unsigned int old = __hip_atomic_fetch_add(cnt, 1u, __ATOMIC_ACQ_REL,
                                                    __HIP_MEMORY_SCOPE_AGENT);
    last = (old == 63u);
  }
  __syncthreads();
  if (last && threadIdx.x < 64) {  // wave 0 of last block reduces 64 pairs
    const float A = wave_sum(__hip_atomic_load(&fin[threadIdx.x * 2],
                                               __ATOMIC_RELAXED,
                                               __HIP_MEMORY_SCOPE_AGENT));
    const float B = wave_sum(__hip_atomic_load(&fin[threadIdx.x * 2 + 1],
                                               __ATOMIC_RELAXED,
                                               __HIP_MEMORY_SCOPE_AGENT));
    if (threadIdx.x == 0) out[0] = A / fmaxf(B, 1e-12f);
  }
}

extern "C" void kernel_launch(void* const* d_in, const int* in_sizes, int n_in,
                              void* d_out, int out_size, void* d_ws, size_t ws_size,
                              hipStream_t stream) {
  const float* x    = (const float*)d_in[0];
  const int*   tgt  = (const int*)d_in[1];
  const int*   nid  = (const int*)d_in[2];
  const float* wts  = (const float*)d_in[3];
  const float* proj = (const float*)d_in[4];
  float* out = (float*)d_out;
  char* ws = (char*)d_ws;
  char* xf = ws + XF_OFF;
  char* ef = ws + EF_OFF;
  float* pl   = (float*)(ws + PL_OFF);
  float* scx  = (float*)(ws + SCX_OFF);
  float* psum = (float*)(ws + PS_OFF);
  float* fin  = (float*)(ws + FP_OFF);
  unsigned int* cnt = (unsigned int*)(ws + CNT_OFF);

  hipLaunchKernelGGL(prep_kernel, dim3(1024 + 512), dim3(256), 0, stream,
                     x, tgt, nid, proj, xf, ef, pl, scx, cnt);
  hipLaunchKernelGGL(flash_kernel, dim3(64 * SSPLIT), dim3(256), 0, stream,
                     xf, ef, scx, psum);
  hipLaunchKernelGGL(finish_kernel, dim3(NROWS / 256), dim3(256), 0, stream,
                     psum, pl, tgt, wts, fin, cnt, out);
}